// Round 4
// baseline (1100.206 us; speedup 1.0000x reference)
//
#include <hip/hip_runtime.h>

// LSTM forward, T=2048, B=1024, I=15, H=10 (PyTorch gate order i,f,g,o).
// Two-kernel split:
//   k1 lstm_pre: pre[t][b][g] = actscale(g) * dot(x[t][b][:], Wih[g,:])  (335 MB in d_ws)
//   k2 lstm_rec: serial recurrence, 4 batch rows per wave (software-interleaved
//                independent chains to fill dependent-latency stalls; rounds 1-3
//                showed per-step cost ~ instr_count x ~8cy, fully serialized).
// Fallback to the fused round-2 kernel if ws_size < PRE_BYTES.

#define T_N 2048
#define B_N 1024
#define I_N 15
#define H_N 10
#define G4  40
#define DQ  8   // prefetch queue depth (steps)
#define RW  4   // batch rows per wave in lstm_rec
#define PRE_BYTES ((size_t)T_N * B_N * G4 * 4)

template <int CTRL>
static __device__ __forceinline__ float qb(float v) {
    // quad_perm broadcast within each group of 4 lanes
    return __builtin_bit_cast(float,
        __builtin_amdgcn_mov_dpp(__builtin_bit_cast(int, v), CTRL, 0xF, 0xF, true));
}
static __device__ __forceinline__ float rl(float v, int lane) {
    return __builtin_bit_cast(float, __builtin_amdgcn_readlane(__builtin_bit_cast(int, v), lane));
}

// ---------------- kernel 1: input projection ----------------
// one thread per (t,b): x row staged via LDS (coalesced loads), Wih via
// scalar (uniform) loads, 40 accumulators, float4 stores.
__global__ __launch_bounds__(256) void lstm_pre(
    const float* __restrict__ x, const float* __restrict__ Wih,
    float* __restrict__ pre)
{
    __shared__ float xs[256][16];
    const int tid = threadIdx.x;
    const int t  = blockIdx.y;
    const int b0 = blockIdx.x * 256;

    // stage x[t][b0..b0+255][0..14] with 15 coalesced 256-wide loads
    const float* xblk = x + ((size_t)t * B_N + b0) * I_N;
#pragma unroll
    for (int i = 0; i < I_N; ++i) {
        const int e = i * 256 + tid;
        xs[e / I_N][e % I_N] = xblk[e];
    }
    __syncthreads();

    float xr[I_N];
#pragma unroll
    for (int i = 0; i < I_N; ++i) xr[i] = xs[tid][i];

    const float LOG2E = 1.4426950408889634f;
    float acc[G4];
#pragma unroll
    for (int g = 0; g < G4; ++g) {
        float a = 0.f;
#pragma unroll
        for (int i = 0; i < I_N; ++i) a = fmaf(xr[i], Wih[g * I_N + i], a);
        // fold activation-argument scale: sigmoid rows -log2e, tanh rows +2log2e
        acc[g] = a * ((g >= 20 && g < 30) ? 2.0f * LOG2E : -LOG2E);
    }

    float4* dst = (float4*)(pre + ((size_t)t * B_N + b0 + tid) * G4);
#pragma unroll
    for (int g = 0; g < G4 / 4; ++g)
        dst[g] = make_float4(acc[4 * g], acc[4 * g + 1], acc[4 * g + 2], acc[4 * g + 3]);
}

// ---------------- kernel 2: recurrence, RW rows per wave ----------------
// lane = 4*j + p (j = hidden unit, p = gate i/f/g/o); lanes 40..63 dup j=9.
__global__ __launch_bounds__(64)
__attribute__((amdgpu_waves_per_eu(1, 1)))
void lstm_rec(const float* __restrict__ pre, const float* __restrict__ h0,
              const float* __restrict__ c0, const float* __restrict__ Whh,
              float* __restrict__ out)
{
    const int lane = threadIdx.x;
    const int p = lane & 3;
    int j = lane >> 2; if (j > H_N - 1) j = H_N - 1;
    const int row = p * H_N + j;
    const int b0 = blockIdx.x * RW;
    const bool isTanh = (p == 2);
    const float LOG2E = 1.4426950408889634f;
    const float sg   = isTanh ? 2.0f * LOG2E : -LOG2E;
    const float Aact = isTanh ? -2.0f : 1.0f;
    const float Bact = isTanh ?  1.0f : 0.0f;

    float whh[H_N];
#pragma unroll
    for (int q = 0; q < H_N; ++q) whh[q] = sg * Whh[row * H_N + q];

    float c[RW], h[RW], hs[RW][H_N];
#pragma unroll
    for (int r = 0; r < RW; ++r) {
        c[r] = c0[(b0 + r) * H_N + j];
        h[r] = h0[(b0 + r) * H_N + j];
#pragma unroll
        for (int q = 0; q < H_N; ++q) hs[r][q] = rl(h[r], 4 * q);
    }

    // prefetch queues: pq[r][d] = pre-scaled gate pre-activation input part
    float pq[RW][DQ];
#pragma unroll
    for (int d = 0; d < DQ; ++d)
#pragma unroll
        for (int r = 0; r < RW; ++r)
            pq[r][d] = pre[((size_t)d * B_N + (b0 + r)) * G4 + row];

    const bool writer = (p == 0) && (lane < 4 * H_N);

    for (int t0 = 0; t0 < T_N; t0 += DQ) {
#pragma unroll
        for (int d = 0; d < DQ; ++d) {
            const int t = t0 + d;
            int tq = t + DQ; if (tq > T_N - 1) tq = T_N - 1;  // uniform -> SALU
#pragma unroll
            for (int r = 0; r < RW; ++r) {
                const float pv = pq[r][d];
                pq[r][d] = pre[((size_t)tq * B_N + (b0 + r)) * G4 + row];

                // recurrent dot: two parallel 5-FMA chains seeded by pre value
                float a3 = pv, a4 = 0.f;
#pragma unroll
                for (int q = 0; q < 5; ++q) a3 = fmaf(hs[r][q],     whh[q],     a3);
#pragma unroll
                for (int q = 0; q < 5; ++q) a4 = fmaf(hs[r][q + 5], whh[q + 5], a4);
                const float acc = a3 + a4;

                // r = 1/(1+exp2(acc)); sigmoid -> r, tanh -> 1-2r
                const float e   = __builtin_amdgcn_exp2f(acc);
                const float rc  = __builtin_amdgcn_rcpf(1.0f + e);
                const float act = fmaf(Aact, rc, Bact);

                // gather i,f,g,o of unit j via quad broadcasts (pure VALU)
                const float iv = qb<0x00>(act);
                const float fv = qb<0x55>(act);
                const float gv = qb<0xAA>(act);
                const float ov = qb<0xFF>(act);

                c[r] = fmaf(fv, c[r], iv * gv);
                const float tt = __builtin_amdgcn_exp2f(c[r] * (2.0f * LOG2E));
                const float th = fmaf(-2.0f, __builtin_amdgcn_rcpf(1.0f + tt), 1.0f);
                h[r] = ov * th;

                if (writer)
                    out[(size_t)t * (B_N * H_N) + (b0 + r) * H_N + j] = h[r];

                // broadcast new h to SGPRs (unit q lives at lane 4q)
#pragma unroll
                for (int q = 0; q < H_N; ++q) hs[r][q] = rl(h[r], 4 * q);
            }
        }
    }

    if (writer) {
        const size_t base = (size_t)T_N * B_N * H_N;
#pragma unroll
        for (int r = 0; r < RW; ++r) {
            out[base + (b0 + r) * H_N + j] = h[r];                        // hN
            out[base + (size_t)B_N * H_N + (b0 + r) * H_N + j] = c[r];    // cN
        }
    }
}

// ---------------- fallback: fused single kernel (round-2 form) ----------------
__global__ __launch_bounds__(64) void lstm_fused(
    const float* __restrict__ x, const float* __restrict__ h0,
    const float* __restrict__ c0, const float* __restrict__ Wih,
    const float* __restrict__ Whh, float* __restrict__ out)
{
    const int b = blockIdx.x;
    const int lane = threadIdx.x;
    const int p = lane & 3;
    int j = lane >> 2; if (j > H_N - 1) j = H_N - 1;
    const int row = p * H_N + j;
    const bool isTanh = (p == 2);
    const float LOG2E = 1.4426950408889634f;
    const float sg   = isTanh ? 2.0f * LOG2E : -LOG2E;
    const float Aact = isTanh ? -2.0f : 1.0f;
    const float Bact = isTanh ?  1.0f : 0.0f;

    float wih[I_N];
#pragma unroll
    for (int i = 0; i < I_N; ++i) wih[i] = sg * Wih[row * I_N + i];
    float whh[H_N];
#pragma unroll
    for (int q = 0; q < H_N; ++q) whh[q] = sg * Whh[row * H_N + q];

    float c = c0[b * H_N + j];
    float h = h0[b * H_N + j];
    float hs[H_N];
#pragma unroll
    for (int q = 0; q < H_N; ++q) hs[q] = rl(h, 4 * q);

    const int xk = lane < I_N ? lane : 0;
    float xq[DQ];
#pragma unroll
    for (int d = 0; d < DQ; ++d)
        xq[d] = x[((size_t)d * B_N + b) * I_N + xk];

    const bool writer = (p == 0) && (lane < 4 * H_N);

    for (int t0 = 0; t0 < T_N; t0 += DQ) {
#pragma unroll
        for (int d = 0; d < DQ; ++d) {
            const int t = t0 + d;
            const float xv = xq[d];
            int tq = t + DQ; if (tq > T_N - 1) tq = T_N - 1;
            xq[d] = x[((size_t)tq * B_N + b) * I_N + xk];

            float a0 = 0.f, a1 = 0.f, a2 = 0.f;
#pragma unroll
            for (int k = 0; k < 5; ++k) a0 = fmaf(rl(xv, k),      wih[k],      a0);
#pragma unroll
            for (int k = 0; k < 5; ++k) a1 = fmaf(rl(xv, k + 5),  wih[k + 5],  a1);
#pragma unroll
            for (int k = 0; k < 5; ++k) a2 = fmaf(rl(xv, k + 10), wih[k + 10], a2);
            const float xpart = (a0 + a1) + a2;

            float a3 = 0.f, a4 = 0.f;
#pragma unroll
            for (int q = 0; q < 5; ++q) a3 = fmaf(hs[q],     whh[q],     a3);
#pragma unroll
            for (int q = 0; q < 5; ++q) a4 = fmaf(hs[q + 5], whh[q + 5], a4);
            const float acc = xpart + (a3 + a4);

            const float e   = __builtin_amdgcn_exp2f(acc);
            const float r   = __builtin_amdgcn_rcpf(1.0f + e);
            const float act = fmaf(Aact, r, Bact);

            const float iv = qb<0x00>(act);
            const float fv = qb<0x55>(act);
            const float gv = qb<0xAA>(act);
            const float ov = qb<0xFF>(act);

            c = fmaf(fv, c, iv * gv);
            const float tt = __builtin_amdgcn_exp2f(c * (2.0f * LOG2E));
            const float th = fmaf(-2.0f, __builtin_amdgcn_rcpf(1.0f + tt), 1.0f);
            h = ov * th;

            if (writer)
                out[(size_t)t * (B_N * H_N) + b * H_N + j] = h;

#pragma unroll
            for (int q = 0; q < H_N; ++q) hs[q] = rl(h, 4 * q);
        }
    }

    if (writer) {
        const size_t base = (size_t)T_N * B_N * H_N;
        out[base + b * H_N + j] = h;
        out[base + (size_t)B_N * H_N + b * H_N + j] = c;
    }
}

extern "C" void kernel_launch(void* const* d_in, const int* in_sizes, int n_in,
                              void* d_out, int out_size, void* d_ws, size_t ws_size,
                              hipStream_t stream) {
    const float* x   = (const float*)d_in[0];
    const float* h0  = (const float*)d_in[1];
    const float* c0  = (const float*)d_in[2];
    const float* Wih = (const float*)d_in[3];
    const float* Whh = (const float*)d_in[4];
    float* out = (float*)d_out;

    if (ws_size >= PRE_BYTES) {
        float* pre = (float*)d_ws;
        lstm_pre<<<dim3(B_N / 256, T_N), dim3(256), 0, stream>>>(x, Wih, pre);
        lstm_rec<<<dim3(B_N / RW), dim3(64), 0, stream>>>(pre, h0, c0, Whh, out);
    } else {
        lstm_fused<<<dim3(B_N), dim3(64), 0, stream>>>(x, h0, c0, Wih, Whh, out);
    }
}

// Round 5
// 568.010 us; speedup vs baseline: 1.9369x; 1.9369x over previous
//
#include <hip/hip_runtime.h>

// LSTM forward, T=2048, B=1024, I=15, H=10 (PyTorch gate order i,f,g,o).
// Split:
//   k1 lstm_pre: pre[t][b][g] = actscale(g)*dot(x[t][b],Wih[g]) stored as f16 (164 MB in d_ws)
//   k2 lstm_rec: serial recurrence, ONE batch row per wave (1024 waves = 1/SIMD).
// Round-4 lesson: wall = T * per-wave-step-cost; interleaving rows into one wave
// shrinks the grid and loses. So: minimize ops/chain of a single-row step.
//   - h broadcast: pack h to f16 pairs (1 DPP row_shl:4 + v_cvt_pkrtz), 5 readlanes
//   - h . Whh: v_dot2_f32_f16 (2 MAC/op, f32 accum), 3-deep chain + 2 parallel
//   - gate combine: DPP quad_perm; activations via exp2/rcp (saturate gracefully)

#define T_N 2048
#define B_N 1024
#define I_N 15
#define H_N 10
#define G4  40
#define DQ  8
#define PRE_BYTES ((size_t)T_N * B_N * G4 * 2)  // f16

typedef _Float16 half2_t __attribute__((ext_vector_type(2)));

#if defined(__has_builtin)
#if __has_builtin(__builtin_amdgcn_fdot2)
#define HAVE_FDOT2 1
#endif
#endif
#ifndef HAVE_FDOT2
#define HAVE_FDOT2 0
#endif

template <int CTRL>
static __device__ __forceinline__ float dppf(float v) {
    return __builtin_bit_cast(float,
        __builtin_amdgcn_mov_dpp(__builtin_bit_cast(int, v), CTRL, 0xF, 0xF, true));
}
static __device__ __forceinline__ float rl(float v, int lane) {
    return __builtin_bit_cast(float, __builtin_amdgcn_readlane(__builtin_bit_cast(int, v), lane));
}
static __device__ __forceinline__ unsigned rlu(unsigned v, int lane) {
    return (unsigned)__builtin_amdgcn_readlane((int)v, lane);
}

// ---------------- kernel 1: input projection -> f16 pre ----------------
__global__ __launch_bounds__(256) void lstm_pre(
    const float* __restrict__ x, const float* __restrict__ Wih,
    unsigned short* __restrict__ pre)
{
    __shared__ float xs[256][16];
    const int tid = threadIdx.x;
    const int t  = blockIdx.y;
    const int b0 = blockIdx.x * 256;

    const float* xblk = x + ((size_t)t * B_N + b0) * I_N;
#pragma unroll
    for (int i = 0; i < I_N; ++i) {
        const int e = i * 256 + tid;
        xs[e / I_N][e % I_N] = xblk[e];
    }
    __syncthreads();

    float xr[I_N];
#pragma unroll
    for (int i = 0; i < I_N; ++i) xr[i] = xs[tid][i];

    const float LOG2E = 1.4426950408889634f;
    float acc[G4];
#pragma unroll
    for (int g = 0; g < G4; ++g) {
        float a = 0.f;
#pragma unroll
        for (int i = 0; i < I_N; ++i) a = fmaf(xr[i], Wih[g * I_N + i], a);
        acc[g] = a * ((g >= 20 && g < 30) ? 2.0f * LOG2E : -LOG2E);
    }

    unsigned pk[G4 / 2];
#pragma unroll
    for (int m = 0; m < G4 / 2; ++m)
        pk[m] = __builtin_bit_cast(unsigned,
                    __builtin_amdgcn_cvt_pkrtz(acc[2 * m], acc[2 * m + 1]));

    uint4* dst = (uint4*)(pre + ((size_t)t * B_N + b0 + tid) * G4);
#pragma unroll
    for (int r = 0; r < G4 / 8; ++r)
        dst[r] = make_uint4(pk[4 * r], pk[4 * r + 1], pk[4 * r + 2], pk[4 * r + 3]);
}

// ---------------- kernel 2: recurrence, 1 row per wave ----------------
// lane = 4*j + p (j = hidden unit, p = gate i/f/g/o); lanes 40..63 dup j=9.
__global__ __launch_bounds__(64)
__attribute__((amdgpu_waves_per_eu(1, 1)))
void lstm_rec(const unsigned short* __restrict__ pre, const float* __restrict__ h0,
              const float* __restrict__ c0, const float* __restrict__ Whh,
              float* __restrict__ out)
{
    const int lane = threadIdx.x;
    const int p = lane & 3;
    int j = lane >> 2; if (j > H_N - 1) j = H_N - 1;
    const int row = p * H_N + j;
    const int b = blockIdx.x;
    const bool isTanh = (p == 2);
    const float LOG2E = 1.4426950408889634f;
    const float sg   = isTanh ? 2.0f * LOG2E : -LOG2E;
    const float Aact = isTanh ? -2.0f : 1.0f;
    const float Bact = isTanh ?  1.0f : 0.0f;

#if HAVE_FDOT2
    // Whh row prescaled, packed to f16 pairs
    half2_t wh2[H_N / 2];
#pragma unroll
    for (int m = 0; m < H_N / 2; ++m) {
        half2_t w;
        w[0] = (_Float16)(sg * Whh[row * H_N + 2 * m]);
        w[1] = (_Float16)(sg * Whh[row * H_N + 2 * m + 1]);
        wh2[m] = w;
    }
#else
    float whh[H_N];
#pragma unroll
    for (int q = 0; q < H_N; ++q) whh[q] = sg * Whh[row * H_N + q];
#endif

    float c = c0[b * H_N + j];
    float h = h0[b * H_N + j];

#if HAVE_FDOT2
    // pack h -> f16 pairs at lanes 8m, broadcast 5 SGPRs
    unsigned hp[5];
    {
        const float hb = dppf<0x104>(h);  // row_shl:4 -> lane i reads lane i+4
        const unsigned pk = __builtin_bit_cast(unsigned, __builtin_amdgcn_cvt_pkrtz(h, hb));
#pragma unroll
        for (int m = 0; m < 5; ++m) hp[m] = rlu(pk, 8 * m);
    }
#else
    float hs[H_N];
#pragma unroll
    for (int q = 0; q < H_N; ++q) hs[q] = rl(h, 4 * q);
#endif

    // prefetch queue of f16 pre values (raw ushort; cvt at use, off-chain)
    unsigned short pq[DQ];
#pragma unroll
    for (int d = 0; d < DQ; ++d)
        pq[d] = pre[((size_t)d * B_N + b) * G4 + row];

    const bool writer = (p == 0) && (lane < 4 * H_N);

    for (int t0 = 0; t0 < T_N; t0 += DQ) {
#pragma unroll
        for (int d = 0; d < DQ; ++d) {
            const int t = t0 + d;
            int tq = t + DQ; if (tq > T_N - 1) tq = T_N - 1;
            const float pv = (float)__builtin_bit_cast(_Float16, pq[d]);
            pq[d] = pre[((size_t)tq * B_N + b) * G4 + row];

#if HAVE_FDOT2
            float a0 = __builtin_amdgcn_fdot2(__builtin_bit_cast(half2_t, hp[0]), wh2[0], pv, false);
            a0       = __builtin_amdgcn_fdot2(__builtin_bit_cast(half2_t, hp[1]), wh2[1], a0, false);
            a0       = __builtin_amdgcn_fdot2(__builtin_bit_cast(half2_t, hp[2]), wh2[2], a0, false);
            float a1 = __builtin_amdgcn_fdot2(__builtin_bit_cast(half2_t, hp[3]), wh2[3], 0.f, false);
            a1       = __builtin_amdgcn_fdot2(__builtin_bit_cast(half2_t, hp[4]), wh2[4], a1, false);
            const float acc = a0 + a1;
#else
            float a0 = pv, a1 = 0.f;
#pragma unroll
            for (int q = 0; q < 5; ++q) a0 = fmaf(hs[q],     whh[q],     a0);
#pragma unroll
            for (int q = 0; q < 5; ++q) a1 = fmaf(hs[q + 5], whh[q + 5], a1);
            const float acc = a0 + a1;
#endif

            // r = 1/(1+exp2(acc)); sigmoid -> r, tanh -> 1-2r (saturates gracefully)
            const float e   = __builtin_amdgcn_exp2f(acc);
            const float rc  = __builtin_amdgcn_rcpf(1.0f + e);
            const float act = fmaf(Aact, rc, Bact);

            // gather i,f,g,o of unit j via quad broadcasts
            const float iv = dppf<0x00>(act);
            const float fv = dppf<0x55>(act);
            const float gv = dppf<0xAA>(act);
            const float ov = dppf<0xFF>(act);

            c = fmaf(fv, c, iv * gv);
            const float tt = __builtin_amdgcn_exp2f(c * (2.0f * LOG2E));
            const float th = fmaf(-2.0f, __builtin_amdgcn_rcpf(1.0f + tt), 1.0f);
            h = ov * th;

            if (writer)
                out[(size_t)t * (B_N * H_N) + b * H_N + j] = h;

#if HAVE_FDOT2
            const float hb = dppf<0x104>(h);
            const unsigned pk = __builtin_bit_cast(unsigned, __builtin_amdgcn_cvt_pkrtz(h, hb));
#pragma unroll
            for (int m = 0; m < 5; ++m) hp[m] = rlu(pk, 8 * m);
#else
#pragma unroll
            for (int q = 0; q < H_N; ++q) hs[q] = rl(h, 4 * q);
#endif
        }
    }

    if (writer) {
        const size_t base = (size_t)T_N * B_N * H_N;
        out[base + b * H_N + j] = h;                           // hN
        out[base + (size_t)B_N * H_N + b * H_N + j] = c;       // cN
    }
}

// ---------------- fallback: fused single kernel (round-2 form) ----------------
__global__ __launch_bounds__(64) void lstm_fused(
    const float* __restrict__ x, const float* __restrict__ h0,
    const float* __restrict__ c0, const float* __restrict__ Wih,
    const float* __restrict__ Whh, float* __restrict__ out)
{
    const int b = blockIdx.x;
    const int lane = threadIdx.x;
    const int p = lane & 3;
    int j = lane >> 2; if (j > H_N - 1) j = H_N - 1;
    const int row = p * H_N + j;
    const bool isTanh = (p == 2);
    const float LOG2E = 1.4426950408889634f;
    const float sg   = isTanh ? 2.0f * LOG2E : -LOG2E;
    const float Aact = isTanh ? -2.0f : 1.0f;
    const float Bact = isTanh ?  1.0f : 0.0f;

    float wih[I_N];
#pragma unroll
    for (int i = 0; i < I_N; ++i) wih[i] = sg * Wih[row * I_N + i];
    float whh[H_N];
#pragma unroll
    for (int q = 0; q < H_N; ++q) whh[q] = sg * Whh[row * H_N + q];

    float c = c0[b * H_N + j];
    float h = h0[b * H_N + j];
    float hs[H_N];
#pragma unroll
    for (int q = 0; q < H_N; ++q) hs[q] = rl(h, 4 * q);

    const int xk = lane < I_N ? lane : 0;
    float xq[DQ];
#pragma unroll
    for (int d = 0; d < DQ; ++d)
        xq[d] = x[((size_t)d * B_N + b) * I_N + xk];

    const bool writer = (p == 0) && (lane < 4 * H_N);

    for (int t0 = 0; t0 < T_N; t0 += DQ) {
#pragma unroll
        for (int d = 0; d < DQ; ++d) {
            const int t = t0 + d;
            const float xv = xq[d];
            int tq = t + DQ; if (tq > T_N - 1) tq = T_N - 1;
            xq[d] = x[((size_t)tq * B_N + b) * I_N + xk];

            float a0 = 0.f, a1 = 0.f, a2 = 0.f;
#pragma unroll
            for (int k = 0; k < 5; ++k) a0 = fmaf(rl(xv, k),      wih[k],      a0);
#pragma unroll
            for (int k = 0; k < 5; ++k) a1 = fmaf(rl(xv, k + 5),  wih[k + 5],  a1);
#pragma unroll
            for (int k = 0; k < 5; ++k) a2 = fmaf(rl(xv, k + 10), wih[k + 10], a2);
            const float xpart = (a0 + a1) + a2;

            float a3 = 0.f, a4 = 0.f;
#pragma unroll
            for (int q = 0; q < 5; ++q) a3 = fmaf(hs[q],     whh[q],     a3);
#pragma unroll
            for (int q = 0; q < 5; ++q) a4 = fmaf(hs[q + 5], whh[q + 5], a4);
            const float acc = xpart + (a3 + a4);

            const float e   = __builtin_amdgcn_exp2f(acc);
            const float r   = __builtin_amdgcn_rcpf(1.0f + e);
            const float act = fmaf(Aact, r, Bact);

            const float iv = dppf<0x00>(act);
            const float fv = dppf<0x55>(act);
            const float gv = dppf<0xAA>(act);
            const float ov = dppf<0xFF>(act);

            c = fmaf(fv, c, iv * gv);
            const float tt = __builtin_amdgcn_exp2f(c * (2.0f * LOG2E));
            const float th = fmaf(-2.0f, __builtin_amdgcn_rcpf(1.0f + tt), 1.0f);
            h = ov * th;

            if (writer)
                out[(size_t)t * (B_N * H_N) + b * H_N + j] = h;

#pragma unroll
            for (int q = 0; q < H_N; ++q) hs[q] = rl(h, 4 * q);
        }
    }

    if (writer) {
        const size_t base = (size_t)T_N * B_N * H_N;
        out[base + b * H_N + j] = h;
        out[base + (size_t)B_N * H_N + b * H_N + j] = c;
    }
}

extern "C" void kernel_launch(void* const* d_in, const int* in_sizes, int n_in,
                              void* d_out, int out_size, void* d_ws, size_t ws_size,
                              hipStream_t stream) {
    const float* x   = (const float*)d_in[0];
    const float* h0  = (const float*)d_in[1];
    const float* c0  = (const float*)d_in[2];
    const float* Wih = (const float*)d_in[3];
    const float* Whh = (const float*)d_in[4];
    float* out = (float*)d_out;

    if (ws_size >= PRE_BYTES) {
        unsigned short* pre = (unsigned short*)d_ws;
        lstm_pre<<<dim3(B_N / 256, T_N), dim3(256), 0, stream>>>(x, Wih, pre);
        lstm_rec<<<dim3(B_N), dim3(64), 0, stream>>>(pre, h0, c0, Whh, out);
    } else {
        lstm_fused<<<dim3(B_N), dim3(64), 0, stream>>>(x, h0, c0, Wih, Whh, out);
    }
}

// Round 6
// 331.365 us; speedup vs baseline: 3.3202x; 1.7142x over previous
//
#include <hip/hip_runtime.h>

// LSTM forward, T=2048, B=1024, I=15, H=10 (PyTorch gate order i,f,g,o).
// Split:
//   k1 lstm_pre: pre[t][b][g] = actscale(g)*dot(x[t][b],Wih[g]) stored f16 (164 MB in d_ws)
//   k2 lstm_rec: serial recurrence, ONE row per wave (1024 waves = 1/SIMD).
// Round-6 structure: the 8-step inner block is PURE ALU. Prefetch loads for the
// next block are burst-issued at block top into a ping-pong queue (pq/pqn);
// h outputs are buffered in regs and stored in one writer-masked burst at block
// end. Theory: round-5's 582cy/step (vs ~150cy chain) = per-step conservative
// vmcnt waits from interleaved load+divergent store; removing all VMEM from the
// step body makes waits block-granular and fully covered.

#define T_N 2048
#define B_N 1024
#define I_N 15
#define H_N 10
#define G4  40
#define DQ  8
#define PRE_BYTES ((size_t)T_N * B_N * G4 * 2)  // f16

typedef _Float16 half2_t __attribute__((ext_vector_type(2)));

template <int CTRL>
static __device__ __forceinline__ float dppf(float v) {
    return __builtin_bit_cast(float,
        __builtin_amdgcn_mov_dpp(__builtin_bit_cast(int, v), CTRL, 0xF, 0xF, true));
}
static __device__ __forceinline__ float rl(float v, int lane) {
    return __builtin_bit_cast(float, __builtin_amdgcn_readlane(__builtin_bit_cast(int, v), lane));
}
static __device__ __forceinline__ unsigned rlu(unsigned v, int lane) {
    return (unsigned)__builtin_amdgcn_readlane((int)v, lane);
}

// ---------------- kernel 1: input projection -> f16 pre ----------------
__global__ __launch_bounds__(256) void lstm_pre(
    const float* __restrict__ x, const float* __restrict__ Wih,
    unsigned short* __restrict__ pre)
{
    __shared__ float xs[256][16];
    const int tid = threadIdx.x;
    const int t  = blockIdx.y;
    const int b0 = blockIdx.x * 256;

    const float* xblk = x + ((size_t)t * B_N + b0) * I_N;
#pragma unroll
    for (int i = 0; i < I_N; ++i) {
        const int e = i * 256 + tid;
        xs[e / I_N][e % I_N] = xblk[e];
    }
    __syncthreads();

    float xr[I_N];
#pragma unroll
    for (int i = 0; i < I_N; ++i) xr[i] = xs[tid][i];

    const float LOG2E = 1.4426950408889634f;
    float acc[G4];
#pragma unroll
    for (int g = 0; g < G4; ++g) {
        float a = 0.f;
#pragma unroll
        for (int i = 0; i < I_N; ++i) a = fmaf(xr[i], Wih[g * I_N + i], a);
        acc[g] = a * ((g >= 20 && g < 30) ? 2.0f * LOG2E : -LOG2E);
    }

    unsigned pk[G4 / 2];
#pragma unroll
    for (int m = 0; m < G4 / 2; ++m)
        pk[m] = __builtin_bit_cast(unsigned,
                    __builtin_amdgcn_cvt_pkrtz(acc[2 * m], acc[2 * m + 1]));

    uint4* dst = (uint4*)(pre + ((size_t)t * B_N + b0 + tid) * G4);
#pragma unroll
    for (int r = 0; r < G4 / 8; ++r)
        dst[r] = make_uint4(pk[4 * r], pk[4 * r + 1], pk[4 * r + 2], pk[4 * r + 3]);
}

// ---------------- kernel 2: recurrence, 1 row per wave ----------------
// lane = 4*j + p (j = hidden unit, p = gate i/f/g/o); lanes 40..63 dup j=9.

// one LSTM step: pure ALU, no memory ops
#define STEP(PQ, d) do {                                                         \
    const float pv = (float)__builtin_bit_cast(_Float16, PQ[d]);                 \
    float a0 = __builtin_amdgcn_fdot2(__builtin_bit_cast(half2_t, hp0), wh2[0], pv,  false); \
    a0       = __builtin_amdgcn_fdot2(__builtin_bit_cast(half2_t, hp1), wh2[1], a0,  false); \
    a0       = __builtin_amdgcn_fdot2(__builtin_bit_cast(half2_t, hp2), wh2[2], a0,  false); \
    float a1 = __builtin_amdgcn_fdot2(__builtin_bit_cast(half2_t, hp3), wh2[3], 0.f, false); \
    a1       = __builtin_amdgcn_fdot2(__builtin_bit_cast(half2_t, hp4), wh2[4], a1,  false); \
    const float accv = a0 + a1;                                                  \
    const float e    = __builtin_amdgcn_exp2f(accv);                             \
    const float rc   = __builtin_amdgcn_rcpf(1.0f + e);                          \
    const float act  = fmaf(Aact, rc, Bact);                                     \
    const float iv = dppf<0x00>(act);                                            \
    const float fv = dppf<0x55>(act);                                            \
    const float gv = dppf<0xAA>(act);                                            \
    const float ov = dppf<0xFF>(act);                                            \
    c = fmaf(fv, c, iv * gv);                                                    \
    const float tt = __builtin_amdgcn_exp2f(c * (2.0f * LOG2E));                 \
    const float th = fmaf(-2.0f, __builtin_amdgcn_rcpf(1.0f + tt), 1.0f);        \
    h = ov * th;                                                                 \
    hbuf[d] = h;                                                                 \
    const float hb = dppf<0x104>(h);  /* row_shl:4 */                            \
    const unsigned pk2 = __builtin_bit_cast(unsigned,                            \
                             __builtin_amdgcn_cvt_pkrtz(h, hb));                 \
    hp0 = rlu(pk2, 0); hp1 = rlu(pk2, 8); hp2 = rlu(pk2, 16);                    \
    hp3 = rlu(pk2, 24); hp4 = rlu(pk2, 32);                                      \
} while (0)

// half-block: burst-prefetch next block into PQN, run 8 pure-ALU steps on PQ,
// burst-store the 8 buffered h values.
#define HALF(PQ, PQN, T0) do {                                                   \
    _Pragma("unroll")                                                            \
    for (int d = 0; d < DQ; ++d) {                                               \
        int tq = (T0) + DQ + d; if (tq > T_N - 1) tq = T_N - 1;                  \
        PQN[d] = pre[((size_t)tq * B_N + b) * G4 + row];                         \
    }                                                                            \
    __builtin_amdgcn_sched_barrier(0);                                           \
    _Pragma("unroll")                                                            \
    for (int d = 0; d < DQ; ++d) { STEP(PQ, d); }                                \
    if (writer) {                                                                \
        _Pragma("unroll")                                                        \
        for (int d = 0; d < DQ; ++d)                                             \
            out[((size_t)((T0) + d)) * (B_N * H_N) + b * H_N + j] = hbuf[d];     \
    }                                                                            \
} while (0)

__global__ __launch_bounds__(64)
__attribute__((amdgpu_waves_per_eu(1, 1)))
void lstm_rec(const unsigned short* __restrict__ pre, const float* __restrict__ h0,
              const float* __restrict__ c0, const float* __restrict__ Whh,
              float* __restrict__ out)
{
    const int lane = threadIdx.x;
    const int p = lane & 3;
    int j = lane >> 2; if (j > H_N - 1) j = H_N - 1;
    const int row = p * H_N + j;
    const int b = blockIdx.x;
    const bool isTanh = (p == 2);
    const float LOG2E = 1.4426950408889634f;
    const float sg   = isTanh ? 2.0f * LOG2E : -LOG2E;
    const float Aact = isTanh ? -2.0f : 1.0f;
    const float Bact = isTanh ?  1.0f : 0.0f;

    // Whh row prescaled, packed to f16 pairs
    half2_t wh2[H_N / 2];
#pragma unroll
    for (int m = 0; m < H_N / 2; ++m) {
        half2_t w;
        w[0] = (_Float16)(sg * Whh[row * H_N + 2 * m]);
        w[1] = (_Float16)(sg * Whh[row * H_N + 2 * m + 1]);
        wh2[m] = w;
    }

    float c = c0[b * H_N + j];
    float h = h0[b * H_N + j];

    // pack h -> f16 pairs at lanes 8m, broadcast 5 SGPRs
    unsigned hp0, hp1, hp2, hp3, hp4;
    {
        const float hb = dppf<0x104>(h);
        const unsigned pk = __builtin_bit_cast(unsigned, __builtin_amdgcn_cvt_pkrtz(h, hb));
        hp0 = rlu(pk, 0); hp1 = rlu(pk, 8); hp2 = rlu(pk, 16);
        hp3 = rlu(pk, 24); hp4 = rlu(pk, 32);
    }

    // ping-pong prefetch queues (raw f16 bits; cvt at use, off-chain)
    unsigned short pq[DQ], pqn[DQ];
#pragma unroll
    for (int d = 0; d < DQ; ++d)
        pq[d] = pre[((size_t)d * B_N + b) * G4 + row];

    float hbuf[DQ];
    const bool writer = (p == 0) && (lane < 4 * H_N);

    for (int t0 = 0; t0 < T_N; t0 += 2 * DQ) {
        HALF(pq, pqn, t0);
        HALF(pqn, pq, t0 + DQ);
    }

    if (writer) {
        const size_t base = (size_t)T_N * B_N * H_N;
        out[base + b * H_N + j] = h;                           // hN
        out[base + (size_t)B_N * H_N + b * H_N + j] = c;       // cN
    }
}

// ---------------- fallback: fused single kernel (round-2 form) ----------------
__global__ __launch_bounds__(64) void lstm_fused(
    const float* __restrict__ x, const float* __restrict__ h0,
    const float* __restrict__ c0, const float* __restrict__ Wih,
    const float* __restrict__ Whh, float* __restrict__ out)
{
    const int b = blockIdx.x;
    const int lane = threadIdx.x;
    const int p = lane & 3;
    int j = lane >> 2; if (j > H_N - 1) j = H_N - 1;
    const int row = p * H_N + j;
    const bool isTanh = (p == 2);
    const float LOG2E = 1.4426950408889634f;
    const float sg   = isTanh ? 2.0f * LOG2E : -LOG2E;
    const float Aact = isTanh ? -2.0f : 1.0f;
    const float Bact = isTanh ?  1.0f : 0.0f;

    float wih[I_N];
#pragma unroll
    for (int i = 0; i < I_N; ++i) wih[i] = sg * Wih[row * I_N + i];
    float whh[H_N];
#pragma unroll
    for (int q = 0; q < H_N; ++q) whh[q] = sg * Whh[row * H_N + q];

    float c = c0[b * H_N + j];
    float h = h0[b * H_N + j];
    float hs[H_N];
#pragma unroll
    for (int q = 0; q < H_N; ++q) hs[q] = rl(h, 4 * q);

    const int xk = lane < I_N ? lane : 0;
    float xq[DQ];
#pragma unroll
    for (int d = 0; d < DQ; ++d)
        xq[d] = x[((size_t)d * B_N + b) * I_N + xk];

    const bool writer = (p == 0) && (lane < 4 * H_N);

    for (int t0 = 0; t0 < T_N; t0 += DQ) {
#pragma unroll
        for (int d = 0; d < DQ; ++d) {
            const int t = t0 + d;
            const float xv = xq[d];
            int tq = t + DQ; if (tq > T_N - 1) tq = T_N - 1;
            xq[d] = x[((size_t)tq * B_N + b) * I_N + xk];

            float a0 = 0.f, a1 = 0.f, a2 = 0.f;
#pragma unroll
            for (int k = 0; k < 5; ++k) a0 = fmaf(rl(xv, k),      wih[k],      a0);
#pragma unroll
            for (int k = 0; k < 5; ++k) a1 = fmaf(rl(xv, k + 5),  wih[k + 5],  a1);
#pragma unroll
            for (int k = 0; k < 5; ++k) a2 = fmaf(rl(xv, k + 10), wih[k + 10], a2);
            const float xpart = (a0 + a1) + a2;

            float a3 = 0.f, a4 = 0.f;
#pragma unroll
            for (int q = 0; q < 5; ++q) a3 = fmaf(hs[q],     whh[q],     a3);
#pragma unroll
            for (int q = 0; q < 5; ++q) a4 = fmaf(hs[q + 5], whh[q + 5], a4);
            const float acc = xpart + (a3 + a4);

            const float e   = __builtin_amdgcn_exp2f(acc);
            const float r   = __builtin_amdgcn_rcpf(1.0f + e);
            const float act = fmaf(Aact, r, Bact);

            const float iv = dppf<0x00>(act);
            const float fv = dppf<0x55>(act);
            const float gv = dppf<0xAA>(act);
            const float ov = dppf<0xFF>(act);

            c = fmaf(fv, c, iv * gv);
            const float tt = __builtin_amdgcn_exp2f(c * (2.0f * LOG2E));
            const float th = fmaf(-2.0f, __builtin_amdgcn_rcpf(1.0f + tt), 1.0f);
            h = ov * th;

            if (writer)
                out[(size_t)t * (B_N * H_N) + b * H_N + j] = h;

#pragma unroll
            for (int q = 0; q < H_N; ++q) hs[q] = rl(h, 4 * q);
        }
    }

    if (writer) {
        const size_t base = (size_t)T_N * B_N * H_N;
        out[base + b * H_N + j] = h;
        out[base + (size_t)B_N * H_N + b * H_N + j] = c;
    }
}

extern "C" void kernel_launch(void* const* d_in, const int* in_sizes, int n_in,
                              void* d_out, int out_size, void* d_ws, size_t ws_size,
                              hipStream_t stream) {
    const float* x   = (const float*)d_in[0];
    const float* h0  = (const float*)d_in[1];
    const float* c0  = (const float*)d_in[2];
    const float* Wih = (const float*)d_in[3];
    const float* Whh = (const float*)d_in[4];
    float* out = (float*)d_out;

    if (ws_size >= PRE_BYTES) {
        unsigned short* pre = (unsigned short*)d_ws;
        lstm_pre<<<dim3(B_N / 256, T_N), dim3(256), 0, stream>>>(x, Wih, pre);
        lstm_rec<<<dim3(B_N), dim3(64), 0, stream>>>(pre, h0, c0, Whh, out);
    } else {
        lstm_fused<<<dim3(B_N), dim3(64), 0, stream>>>(x, h0, c0, Wih, Whh, out);
    }
}

// Round 7
// 320.670 us; speedup vs baseline: 3.4310x; 1.0334x over previous
//
#include <hip/hip_runtime.h>

// LSTM forward, fused single kernel. T=2048, B=1024, I=15, H=10 (gate order i,f,g,o).
// One wave per batch row (1024 waves = 1 wave/SIMD, structural; serial over T).
// Lane layout: lane = 4*j + p (j = hidden unit, p = gate i/f/g/o); lanes 40..63 dup j=9.
//
// Round-6 lesson (measured): step cost == recurrent chain latency (~310cy), with
// ~160cy/step of VALU issue slack hidden in chain stalls. So the x.Wih projection
// (previously a separate 67us kernel + 335MB of workspace traffic) is folded back
// into the step as off-chain work: packed-f16 x pairs + fdot2, seeding the h-chain.
// Chain micro-cuts: cell state carried pre-scaled (cs = 2log2e*c; scale folded into
// the g-gate activation constants) removes the mul before the tanh exp2.
// Inner 16-step block is PURE ALU: x loads burst-prefetched into ping-pong reg
// queues at block top; h buffered in regs, one writer-masked store burst at end.

#define T_N 2048
#define B_N 1024
#define I_N 15
#define H_N 10
#define DQ  16  // steps per block (prefetch/store burst granularity)

typedef _Float16 half2_t __attribute__((ext_vector_type(2)));

template <int CTRL>
static __device__ __forceinline__ float dppf(float v) {
    return __builtin_bit_cast(float,
        __builtin_amdgcn_mov_dpp(__builtin_bit_cast(int, v), CTRL, 0xF, 0xF, true));
}
static __device__ __forceinline__ unsigned rlu(unsigned v, int lane) {
    return (unsigned)__builtin_amdgcn_readlane((int)v, lane);
}
static __device__ __forceinline__ half2_t h2(unsigned u) {
    return __builtin_bit_cast(half2_t, u);
}

// one LSTM step: pure ALU, no memory ops.
// XQ[d] = x element (lane i holds x[t][b][i], i<15); chain state: cs, hp0..hp4.
#define STEP(XQ, d) do {                                                          \
    /* ---- x projection (off-chain): pack x to f16 pairs, broadcast, fdot2 ---- */\
    const float xv = XQ[d];                                                       \
    const float xnb = dppf<0x101>(xv);                 /* lane i reads i+1 */     \
    const unsigned xpk = __builtin_bit_cast(unsigned,                             \
                             __builtin_amdgcn_cvt_pkrtz(xv, xnb));                \
    const unsigned xs0 = rlu(xpk, 0),  xs1 = rlu(xpk, 2),  xs2 = rlu(xpk, 4);     \
    const unsigned xs3 = rlu(xpk, 6),  xs4 = rlu(xpk, 8),  xs5 = rlu(xpk, 10);    \
    const unsigned xs6 = rlu(xpk, 12), xs7 = rlu(xpk, 14);                        \
    float xa = __builtin_amdgcn_fdot2(h2(xs0), wx[0], 0.f, false);                \
    xa       = __builtin_amdgcn_fdot2(h2(xs1), wx[1], xa,  false);                \
    xa       = __builtin_amdgcn_fdot2(h2(xs2), wx[2], xa,  false);                \
    xa       = __builtin_amdgcn_fdot2(h2(xs3), wx[3], xa,  false);                \
    float xb2 = __builtin_amdgcn_fdot2(h2(xs4), wx[4], 0.f, false);               \
    xb2       = __builtin_amdgcn_fdot2(h2(xs5), wx[5], xb2, false);               \
    xb2       = __builtin_amdgcn_fdot2(h2(xs6), wx[6], xb2, false);               \
    xb2       = __builtin_amdgcn_fdot2(h2(xs7), wx[7], xb2, false);               \
    const float xacc = xa + xb2;                                                  \
    /* ---- recurrent dot (chain): 3-deep fdot2 seeded by xacc, + 2 parallel --- */\
    float a0 = __builtin_amdgcn_fdot2(h2(hp0), wh[0], xacc, false);               \
    a0       = __builtin_amdgcn_fdot2(h2(hp1), wh[1], a0,   false);               \
    a0       = __builtin_amdgcn_fdot2(h2(hp2), wh[2], a0,   false);               \
    float a1 = __builtin_amdgcn_fdot2(h2(hp3), wh[3], 0.f,  false);               \
    a1       = __builtin_amdgcn_fdot2(h2(hp4), wh[4], a1,   false);               \
    const float acc = a0 + a1;                                                    \
    /* ---- activation: r = 1/(1+exp2(acc)); sigmoid -> r, tanh -> scaled ------ */\
    const float e   = __builtin_amdgcn_exp2f(acc);                                \
    const float rc  = __builtin_amdgcn_rcpf(1.0f + e);                            \
    const float act = fmaf(Aact, rc, Bact);                                       \
    /* ---- gate combine via quad broadcasts ---------------------------------- */\
    const float iv = dppf<0x00>(act);                                             \
    const float fv = dppf<0x55>(act);                                             \
    const float gv = dppf<0xAA>(act);   /* pre-scaled by 2log2e */                \
    const float ov = dppf<0xFF>(act);                                             \
    /* ---- cell (pre-scaled) + hidden ---------------------------------------- */\
    cs = fmaf(fv, cs, iv * gv);         /* cs = 2log2e * c */                     \
    const float tt = __builtin_amdgcn_exp2f(cs);                                  \
    const float th = fmaf(-2.0f, __builtin_amdgcn_rcpf(1.0f + tt), 1.0f);         \
    h = ov * th;                                                                  \
    hbuf[d] = h;                                                                  \
    /* ---- pack + broadcast h for next step ---------------------------------- */\
    const float hb = dppf<0x104>(h);    /* lane i reads i+4 */                    \
    const unsigned pk2 = __builtin_bit_cast(unsigned,                             \
                             __builtin_amdgcn_cvt_pkrtz(h, hb));                  \
    hp0 = rlu(pk2, 0); hp1 = rlu(pk2, 8); hp2 = rlu(pk2, 16);                     \
    hp3 = rlu(pk2, 24); hp4 = rlu(pk2, 32);                                       \
} while (0)

// half-block: burst-prefetch next block's x into XQN, run DQ pure-ALU steps on
// XQ, burst-store the DQ buffered h values.
#define HALF(XQ, XQN, T0) do {                                                    \
    _Pragma("unroll")                                                             \
    for (int d = 0; d < DQ; ++d) {                                                \
        int tq = (T0) + DQ + d; if (tq > T_N - 1) tq = T_N - 1;                   \
        XQN[d] = xlane[(size_t)tq * (B_N * I_N)];                                 \
    }                                                                             \
    __builtin_amdgcn_sched_barrier(0);                                            \
    _Pragma("unroll")                                                             \
    for (int d = 0; d < DQ; ++d) { STEP(XQ, d); }                                 \
    if (writer) {                                                                 \
        _Pragma("unroll")                                                         \
        for (int d = 0; d < DQ; ++d)                                              \
            out[((size_t)((T0) + d)) * (B_N * H_N) + b * H_N + j] = hbuf[d];      \
    }                                                                             \
} while (0)

__global__ __launch_bounds__(64)
__attribute__((amdgpu_waves_per_eu(1, 1)))
void lstm_all(const float* __restrict__ x, const float* __restrict__ h0,
              const float* __restrict__ c0, const float* __restrict__ Wih,
              const float* __restrict__ Whh, float* __restrict__ out)
{
    const int lane = threadIdx.x;
    const int p = lane & 3;                               // gate: 0=i 1=f 2=g 3=o
    int j = lane >> 2; if (j > H_N - 1) j = H_N - 1;      // lanes 40..63 dup j=9
    const int row = p * H_N + j;                          // W row ([i;f;g;o] x 10)
    const int b = blockIdx.x;
    const bool isTanh = (p == 2);
    const float LOG2E = 1.4426950408889634f;
    // weight prescale: sigmoid rows -log2e (r=1/(1+2^acc)=sigmoid),
    //                  tanh row +2log2e (tanh = 1-2r)
    const float sg = isTanh ? 2.0f * LOG2E : -LOG2E;
    // activation constants; g-gate additionally pre-scaled by 2log2e so the
    // carried cell state cs = 2log2e*c feeds exp2 directly (saves a chain mul):
    //   g: act = 2log2e*(1-2r) = fma(-4log2e, r, 2log2e);  sigmoid: act = r
    const float Aact = isTanh ? -4.0f * LOG2E : 1.0f;
    const float Bact = isTanh ?  2.0f * LOG2E : 0.0f;

    // Wih row prescaled -> f16 pairs (pair 7 = (w14, 0); lane i+1 garbage killed)
    half2_t wx[8];
#pragma unroll
    for (int m = 0; m < 7; ++m) {
        half2_t w;
        w[0] = (_Float16)(sg * Wih[row * I_N + 2 * m]);
        w[1] = (_Float16)(sg * Wih[row * I_N + 2 * m + 1]);
        wx[m] = w;
    }
    { half2_t w; w[0] = (_Float16)(sg * Wih[row * I_N + 14]); w[1] = (_Float16)0.0f; wx[7] = w; }

    // Whh row prescaled -> f16 pairs
    half2_t wh[5];
#pragma unroll
    for (int m = 0; m < 5; ++m) {
        half2_t w;
        w[0] = (_Float16)(sg * Whh[row * H_N + 2 * m]);
        w[1] = (_Float16)(sg * Whh[row * H_N + 2 * m + 1]);
        wh[m] = w;
    }

    float cs = c0[b * H_N + j] * (2.0f * LOG2E);   // pre-scaled cell state
    float h  = h0[b * H_N + j];

    // pack h -> f16 pairs at lanes 8m, broadcast 5 SGPRs
    unsigned hp0, hp1, hp2, hp3, hp4;
    {
        const float hb = dppf<0x104>(h);
        const unsigned pk = __builtin_bit_cast(unsigned, __builtin_amdgcn_cvt_pkrtz(h, hb));
        hp0 = rlu(pk, 0); hp1 = rlu(pk, 8); hp2 = rlu(pk, 16);
        hp3 = rlu(pk, 24); hp4 = rlu(pk, 32);
    }

    // x prefetch: lane i<15 carries x[t][b][i]; others dup element 0 (same line)
    const int xk = lane < I_N ? lane : 0;
    const float* xlane = x + (size_t)b * I_N + xk;
    float xq[DQ], xqn[DQ];
#pragma unroll
    for (int d = 0; d < DQ; ++d)
        xq[d] = xlane[(size_t)d * (B_N * I_N)];

    float hbuf[DQ];
    const bool writer = (p == 0) && (lane < 4 * H_N);

    for (int t0 = 0; t0 < T_N; t0 += 2 * DQ) {
        HALF(xq, xqn, t0);
        HALF(xqn, xq, t0 + DQ);
    }

    // final hN, cN appended after out (flat tuple order: out, hN, cN)
    if (writer) {
        const size_t base = (size_t)T_N * B_N * H_N;
        out[base + b * H_N + j] = h;                                    // hN
        out[base + (size_t)B_N * H_N + b * H_N + j] = cs * 0.34657359027997264f; // cN = cs/(2log2e)
    }
}

extern "C" void kernel_launch(void* const* d_in, const int* in_sizes, int n_in,
                              void* d_out, int out_size, void* d_ws, size_t ws_size,
                              hipStream_t stream) {
    const float* x   = (const float*)d_in[0];
    const float* h0  = (const float*)d_in[1];
    const float* c0  = (const float*)d_in[2];
    const float* Wih = (const float*)d_in[3];
    const float* Whh = (const float*)d_in[4];
    float* out = (float*)d_out;
    lstm_all<<<dim3(B_N), dim3(64), 0, stream>>>(x, h0, c0, Wih, Whh, out);
}